// Round 6
// baseline (229.106 us; speedup 1.0000x reference)
//
#include <hip/hip_runtime.h>
#include <hip/hip_bf16.h>
#include <cstdint>

typedef __bf16 bf16_t;
typedef __attribute__((ext_vector_type(8))) __bf16 bf16x8;
typedef __attribute__((ext_vector_type(4))) __bf16 bf16x4;
typedef __attribute__((ext_vector_type(4))) float f32x4;

#define B_ 4
#define S_ 2048
#define E_ 1024
#define H_ 16
#define D_ 64

// Q pre-scale: (1/sqrt(D)) * log2(e) so softmax exp becomes a bare v_exp_f32 (2^x)
#define QSCALE 0.18033688011112042f

// ---------------- f32 -> bf16 conversion (vectorized) ----------------
__global__ void cvt_f32_to_bf16(const float* __restrict__ in, bf16_t* __restrict__ out, int n4) {
    int i = blockIdx.x * blockDim.x + threadIdx.x;
    int stride = gridDim.x * blockDim.x;
    for (; i < n4; i += stride) {
        f32x4 v = reinterpret_cast<const f32x4*>(in)[i];
        bf16x4 o;
        o.x = (bf16_t)v.x; o.y = (bf16_t)v.y; o.z = (bf16_t)v.z; o.w = (bf16_t)v.w;
        reinterpret_cast<bf16x4*>(out)[i] = o;
    }
}

// ---------------- async global->LDS helper ----------------
__device__ __forceinline__ void gload_lds16(const bf16_t* g, bf16_t* l) {
    __builtin_amdgcn_global_load_lds((const __attribute__((address_space(1))) void*)g,
                                     (__attribute__((address_space(3))) void*)l, 16, 0, 0);
}

__device__ __forceinline__ void wait_vm3() { asm volatile("s_waitcnt vmcnt(3)" ::: "memory"); }
__device__ __forceinline__ void wait_vm0() { asm volatile("s_waitcnt vmcnt(0)" ::: "memory"); }

// ---------------- deep-pipelined bf16 GEMM: C[m,f] = sum_e A[m,e]*B[f,e] (+bias) ----
// Tile 128x256, BK=32, 512 threads (8 waves 2Mx4N, 64x64 per wave).
// 3-buffer LDS (72 KiB), depth-2 staged-ahead pipeline: per K-tile exactly one
// s_barrier + one counted vmcnt(3) (vmcnt(0) only at the final tile).
// Buffer (kt+2)%3 written during iter kt was last read in iter kt-1 -> race-free.
// LDS: two 64B rows per 128B line, 16B-chunk XOR swizzle (inverse-swizzled global
// source + swizzled ds_read) -> fragment reads are bank-conflict-free bijections.
// MODE 0: QKV epilogue -> Q [B,H,S,D] (scaled), K [B,H,S,D], Vt [B,H,D,S]
// MODE 1: f32 epilogue -> Outf[m*N+f] = acc + bias[f]
template <int MODE>
__launch_bounds__(512, 2)
__global__ void gemm_pipe(const bf16_t* __restrict__ A, const bf16_t* __restrict__ Bm,
                          const float* __restrict__ bias,
                          int M, int N,
                          bf16_t* __restrict__ Qg, bf16_t* __restrict__ Kg,
                          bf16_t* __restrict__ Vtg, float* __restrict__ Outf) {
    constexpr int K = 1024, BK = 32, NKT = K / BK;   // 32 K-tiles
    constexpr int BM = 128, BN = 256;
    __shared__ __align__(16) bf16_t As[3][BM * BK];  // 3 x 8 KiB
    __shared__ __align__(16) bf16_t Bs[3][BN * BK];  // 3 x 16 KiB

    // bijective XCD swizzle (grid % 8 == 0 for all our launches)
    const int nwg = gridDim.x;
    const int cpx = nwg >> 3;
    const int bid = (blockIdx.x & 7) * cpx + (blockIdx.x >> 3);

    const int nTN = N / BN;
    const int mt = bid / nTN, nt = bid % nTN;
    const int m0 = mt * BM, n0 = nt * BN;

    const int t = threadIdx.x;
    const int lane = t & 63;
    const int wid = t >> 6;              // 0..7
    const int wr = wid >> 2, wc = wid & 3;  // 2M x 4N
    const int lr = lane & 15, lg = lane >> 4;

    // ---- staging sources (inverse-swizzled global addresses, linear LDS dest) ----
    // chunk c (16B): line = c>>3, ch = c&7; global chunk chg = ch ^ (line&7);
    // global row = 2*line + (chg>>2), k-offset = (chg&3)*8.
    const int cA = t;                          // A: 512 chunks, 1/thread
    {
    }
    const int lineA = cA >> 3, chgA = (cA & 7) ^ (lineA & 7);
    const bf16_t* aSrc = A + (int64_t)(m0 + 2 * lineA + (chgA >> 2)) * K + (chgA & 3) * 8;

    const int cB0 = t, cB1 = t + 512;          // B: 1024 chunks, 2/thread
    const int lineB0 = cB0 >> 3, chgB0 = (cB0 & 7) ^ (lineB0 & 7);
    const int lineB1 = cB1 >> 3, chgB1 = (cB1 & 7) ^ (lineB1 & 7);
    const bf16_t* bSrc0 = Bm + (int64_t)(n0 + 2 * lineB0 + (chgB0 >> 2)) * K + (chgB0 & 3) * 8;
    const bf16_t* bSrc1 = Bm + (int64_t)(n0 + 2 * lineB1 + (chgB1 >> 2)) * K + (chgB1 & 3) * 8;

    auto stageT = [&](int kt, int buf) {
        gload_lds16(aSrc + kt * BK, &As[buf][cA * 8]);
        gload_lds16(bSrc0 + kt * BK, &Bs[buf][cB0 * 8]);
        gload_lds16(bSrc1 + kt * BK, &Bs[buf][cB1 * 8]);
    };

    // swizzled fragment element offset for (row, k-chunk lg)
    auto fragOff = [](int row, int kc) -> int {
        const int line = row >> 1;
        const int ch = ((row & 1) << 2) | kc;
        return line * 64 + ((ch ^ (line & 7)) << 3);
    };

    f32x4 acc[4][4] = {};

    stageT(0, 0);
    stageT(1, 1);

    int bufc = 0, bufs = 2;
    for (int kt = 0; kt < NKT; ++kt) {
        if (kt < NKT - 1) wait_vm3(); else wait_vm0();
        __builtin_amdgcn_s_barrier();
        __builtin_amdgcn_sched_barrier(0);

        if (kt + 2 < NKT) stageT(kt + 2, bufs);

        bf16x8 bfr[4], afr[4];
#pragma unroll
        for (int j = 0; j < 4; ++j)
            bfr[j] = *(const bf16x8*)&Bs[bufc][fragOff(wc * 64 + j * 16 + lr, lg)];
#pragma unroll
        for (int i = 0; i < 4; ++i)
            afr[i] = *(const bf16x8*)&As[bufc][fragOff(wr * 64 + i * 16 + lr, lg)];

        __builtin_amdgcn_s_setprio(1);
#pragma unroll
        for (int i = 0; i < 4; ++i)
#pragma unroll
            for (int j = 0; j < 4; ++j)
                acc[i][j] = __builtin_amdgcn_mfma_f32_16x16x32_bf16(afr[i], bfr[j], acc[i][j], 0, 0, 0);
        __builtin_amdgcn_s_setprio(0);

        bufc = (bufc == 2) ? 0 : bufc + 1;
        bufs = (bufs == 2) ? 0 : bufs + 1;
    }

    // ---------------- epilogue ----------------
    if (MODE == 0) {
        const int which = n0 >> 10;   // 0=Q 1=K 2=V (BN=256 divides E)
#pragma unroll
        for (int j = 0; j < 4; ++j) {
            const int f = n0 + wc * 64 + j * 16 + lr;
            const float bv = bias[f];
            const int fe = f - which * E_;
            const int h = fe >> 6, d = fe & 63;
#pragma unroll
            for (int i = 0; i < 4; ++i) {
#pragma unroll
                for (int r = 0; r < 4; ++r) {
                    const int m = m0 + wr * 64 + i * 16 + lg * 4 + r;
                    const int b = m >> 11, si = m & (S_ - 1);
                    const float v = acc[i][j][r] + bv;
                    if (which == 0)
                        Qg[(((int64_t)(b * H_ + h)) * S_ + si) * D_ + d] = (bf16_t)(v * QSCALE);
                    else if (which == 1)
                        Kg[(((int64_t)(b * H_ + h)) * S_ + si) * D_ + d] = (bf16_t)v;
                    else
                        Vtg[(((int64_t)(b * H_ + h)) * D_ + d) * S_ + si] = (bf16_t)v;
                }
            }
        }
    } else {
#pragma unroll
        for (int j = 0; j < 4; ++j) {
            const int f = n0 + wc * 64 + j * 16 + lr;
            const float bv = bias[f];
#pragma unroll
            for (int i = 0; i < 4; ++i) {
#pragma unroll
                for (int r = 0; r < 4; ++r) {
                    const int m = m0 + wr * 64 + i * 16 + lg * 4 + r;
                    Outf[(int64_t)m * N + f] = acc[i][j][r] + bv;
                }
            }
        }
    }
}

// ---------------- flash-style causal attention, work-balanced pairs ----------------
// No-max softmax (scores bounded far below f32-exp overflow); Q pre-scaled by
// log2(e)/sqrt(D) so p = 2^s via one v_exp_f32. Row-sum via ones-MFMA.
__launch_bounds__(256, 4)
__global__ void attn_causal(const bf16_t* __restrict__ Qg, const bf16_t* __restrict__ Kg,
                            const bf16_t* __restrict__ Vtg, bf16_t* __restrict__ Og) {
    __shared__ __align__(16) bf16_t Ks[2][64 * 64];   // 16 KiB
    __shared__ __align__(16) bf16_t Vs[2][64 * 64];   // 16 KiB
    __shared__ __align__(16) bf16_t P_lds[4][16 * 64]; // 8 KiB, swizzled

    const int bid = blockIdx.x;
    const int xcd = bid & 7, j = bid >> 3;
    const int bh = (j >> 4) * 8 + xcd;
    const int i = j & 15;
    const int qtA = i, qtB = 31 - i;

    const int t = threadIdx.x, lane = t & 63, w = t >> 6;
    const int lr = lane & 15, lg = lane >> 4;
    const int q0A = qtA * 64 + w * 16;
    const int q0B = qtB * 64 + w * 16;

    const bf16_t* Qb = Qg + (int64_t)bh * S_ * D_;
    const bf16_t* Kb = Kg + (int64_t)bh * S_ * D_;
    const bf16_t* Vb = Vtg + (int64_t)bh * D_ * S_;

    const int srow = t >> 3;
    const int scol_sw = (t & 7) ^ (srow & 7);

    auto stageK = [&](int buf, int kv0) {
        const bf16_t* base = Kb + (kv0 + srow) * D_ + scol_sw * 8;
        gload_lds16(base, &Ks[buf][t * 8]);
        gload_lds16(base + 32 * D_, &Ks[buf][t * 8 + 2048]);
    };
    auto stageV = [&](int buf, int kv0) {
        const bf16_t* base = Vb + srow * S_ + kv0 + scol_sw * 8;
        gload_lds16(base, &Vs[buf][t * 8]);
        gload_lds16(base + 32 * S_, &Vs[buf][t * 8 + 2048]);
    };

    auto psw = [](int row, int col) {
        return row * 64 + ((((col >> 3) ^ (row & 7)) << 3) | (col & 7));
    };

    bf16x8 qfA[2], qfB[2];
#pragma unroll
    for (int kk = 0; kk < 2; ++kk) {
        qfA[kk] = *(const bf16x8*)&Qb[(q0A + lr) * D_ + kk * 32 + lg * 8];
        qfB[kk] = *(const bf16x8*)&Qb[(q0B + lr) * D_ + kk * 32 + lg * 8];
    }

    bf16x8 ones;
#pragma unroll
    for (int e = 0; e < 8; ++e) ones[e] = (bf16_t)1.0f;

    f32x4 oA[4] = {}, oB[4] = {};
    f32x4 lA = {}, lB = {};

    int cur = 0;
    stageK(0, 0);
    stageV(0, 0);
    __syncthreads();

    for (int tkv = 0; tkv <= qtB; ++tkv) {
        const int kv0 = tkv * 64;
        if (tkv < qtB) { stageK(cur ^ 1, kv0 + 64); stageV(cur ^ 1, kv0 + 64); }

        auto process = [&](int q0, const bf16x8* qf, f32x4* o, f32x4& accl, bf16_t* Pw) {
            f32x4 sc[4] = {};
            __builtin_amdgcn_s_setprio(1);
#pragma unroll
            for (int nj = 0; nj < 4; ++nj) {
                if (kv0 + nj * 16 <= q0 + 15) {   // skip fully-masked sub-tiles (wave-uniform)
                    const int krow = nj * 16 + lr;
#pragma unroll
                    for (int kk = 0; kk < 2; ++kk) {
                        bf16x8 kfr = *(const bf16x8*)&Ks[cur][krow * 64 + (((kk * 4 + lg) ^ (krow & 7)) * 8)];
                        sc[nj] = __builtin_amdgcn_mfma_f32_16x16x32_bf16(qf[kk], kfr, sc[nj], 0, 0, 0);
                    }
                }
            }
            __builtin_amdgcn_s_setprio(0);

            if (kv0 + 64 > q0) {  // causal mask (boundary tile only)
#pragma unroll
                for (int nj = 0; nj < 4; ++nj) {
                    const int col = kv0 + nj * 16 + lr;
#pragma unroll
                    for (int r = 0; r < 4; ++r) {
                        const int rowg = q0 + lg * 4 + r;
                        if (col > rowg) sc[nj][r] = -1e30f;
                    }
                }
            }

            // p = 2^s; masked -> 0
#pragma unroll
            for (int nj = 0; nj < 4; ++nj)
#pragma unroll
                for (int r = 0; r < 4; ++r)
                    Pw[psw(lg * 4 + r, nj * 16 + lr)] = (bf16_t)__builtin_amdgcn_exp2f(sc[nj][r]);
            asm volatile("s_waitcnt lgkmcnt(0)" ::: "memory");
            __builtin_amdgcn_sched_barrier(0);

            __builtin_amdgcn_s_setprio(1);
#pragma unroll
            for (int kk = 0; kk < 2; ++kk) {
                bf16x8 pa = *(const bf16x8*)&Pw[psw(lr, kk * 32 + lg * 8)];
                accl = __builtin_amdgcn_mfma_f32_16x16x32_bf16(pa, ones, accl, 0, 0, 0);
#pragma unroll
                for (int nd = 0; nd < 4; ++nd) {
                    const int vrow = nd * 16 + lr;
                    bf16x8 vf = *(const bf16x8*)&Vs[cur][vrow * 64 + (((kk * 4 + lg) ^ (vrow & 7)) * 8)];
                    o[nd] = __builtin_amdgcn_mfma_f32_16x16x32_bf16(pa, vf, o[nd], 0, 0, 0);
                }
            }
            __builtin_amdgcn_s_setprio(0);
        };

        process(q0B, qfB, oB, lB, &P_lds[w][0]);
        if (tkv <= qtA) process(q0A, qfA, oA, lA, &P_lds[w][0]);

        __syncthreads();
        cur ^= 1;
    }

    const int b = bh >> 4, h = bh & 15;
#pragma unroll
    for (int r = 0; r < 4; ++r) {
        const float rlA = 1.0f / lA[r];
        const float rlB = 1.0f / lB[r];
        const int rA = q0A + lg * 4 + r;
        const int rB = q0B + lg * 4 + r;
#pragma unroll
        for (int nd = 0; nd < 4; ++nd) {
            Og[((int64_t)(b * S_ + rA)) * E_ + h * D_ + nd * 16 + lr] = (bf16_t)(oA[nd][r] * rlA);
            Og[((int64_t)(b * S_ + rB)) * E_ + h * D_ + nd * 16 + lr] = (bf16_t)(oB[nd][r] * rlB);
        }
    }
}

// ---------------- launch ----------------
extern "C" void kernel_launch(void* const* d_in, const int* in_sizes, int n_in,
                              void* d_out, int out_size, void* d_ws, size_t ws_size,
                              hipStream_t stream) {
    const float* x    = (const float*)d_in[0];
    const float* Wa_w = (const float*)d_in[1];
    const float* Wa_b = (const float*)d_in[2];
    const float* Wo_w = (const float*)d_in[3];
    const float* Wo_b = (const float*)d_in[4];
    float* out = (float*)d_out;

    const size_t M = (size_t)B_ * S_;       // 8192
    char* ws = (char*)d_ws;
    bf16_t* xb  = (bf16_t*)ws; ws += M * E_ * 2;
    bf16_t* wab = (bf16_t*)ws; ws += (size_t)3 * E_ * E_ * 2;
    bf16_t* wob = (bf16_t*)ws; ws += (size_t)E_ * E_ * 2;
    bf16_t* Qg  = (bf16_t*)ws; ws += M * E_ * 2;
    bf16_t* Kg  = (bf16_t*)ws; ws += M * E_ * 2;
    bf16_t* Vtg = (bf16_t*)ws; ws += M * E_ * 2;
    bf16_t* Og  = (bf16_t*)ws; ws += M * E_ * 2;

    cvt_f32_to_bf16<<<2048, 256, 0, stream>>>(x, xb, (int)(M * E_ / 4));
    cvt_f32_to_bf16<<<768, 256, 0, stream>>>(Wa_w, wab, 3 * E_ * E_ / 4);
    cvt_f32_to_bf16<<<256, 256, 0, stream>>>(Wo_w, wob, E_ * E_ / 4);

    // QKV projection: M=8192, N=3072 -> 64 x 12 = 768 blocks (3 clean rounds/CU)
    gemm_pipe<0><<<768, 512, 0, stream>>>(
        xb, wab, Wa_b, 8192, 3072, Qg, Kg, Vtg, nullptr);

    // causal attention (work-balanced pairs, 4 blocks/CU, zero tail, no-max softmax)
    attn_causal<<<B_ * H_ * 16, 256, 0, stream>>>(Qg, Kg, Vtg, Og);

    // output projection: M=8192, N=1024 -> 64 x 4 = 256 blocks (1 round/CU)
    gemm_pipe<1><<<256, 512, 0, stream>>>(
        Og, wob, Wo_b, 8192, 1024, nullptr, nullptr, nullptr, out);
}

// Round 7
// 190.617 us; speedup vs baseline: 1.2019x; 1.2019x over previous
//
#include <hip/hip_runtime.h>
#include <hip/hip_bf16.h>
#include <cstdint>

typedef __bf16 bf16_t;
typedef __attribute__((ext_vector_type(8))) __bf16 bf16x8;
typedef __attribute__((ext_vector_type(4))) __bf16 bf16x4;
typedef __attribute__((ext_vector_type(4))) float f32x4;

#define B_ 4
#define S_ 2048
#define E_ 1024
#define H_ 16
#define D_ 64

// Q pre-scale: (1/sqrt(D)) * log2(e) so softmax exp becomes a bare v_exp_f32 (2^x)
#define QSCALE 0.18033688011112042f

// ---------------- f32 -> bf16 conversion (vectorized) ----------------
__global__ void cvt_f32_to_bf16(const float* __restrict__ in, bf16_t* __restrict__ out, int n4) {
    int i = blockIdx.x * blockDim.x + threadIdx.x;
    int stride = gridDim.x * blockDim.x;
    for (; i < n4; i += stride) {
        f32x4 v = reinterpret_cast<const f32x4*>(in)[i];
        bf16x4 o;
        o.x = (bf16_t)v.x; o.y = (bf16_t)v.y; o.z = (bf16_t)v.z; o.w = (bf16_t)v.w;
        reinterpret_cast<bf16x4*>(out)[i] = o;
    }
}

// ---------------- async global->LDS helper ----------------
__device__ __forceinline__ void gload_lds16(const bf16_t* g, bf16_t* l) {
    __builtin_amdgcn_global_load_lds((const __attribute__((address_space(1))) void*)g,
                                     (__attribute__((address_space(3))) void*)l, 16, 0, 0);
}

__device__ __forceinline__ void wait_vm4() { asm volatile("s_waitcnt vmcnt(4)" ::: "memory"); }
__device__ __forceinline__ void wait_vm0() { asm volatile("s_waitcnt vmcnt(0)" ::: "memory"); }

// ---------------- deep-pipelined bf16 GEMM: C[m,f] = sum_e A[m,e]*B[f,e] (+bias) ----
// Tile 128x128, BK=32, 256 threads (4 waves 2x2, 64x64 per wave).
// 3-buffer LDS (48 KiB -> 3 blocks/CU), depth-2 staged-ahead pipeline: per K-tile
// exactly one s_barrier + one counted vmcnt(4) (vmcnt(0) only at the final tile).
// Grid sized for clean residency: QKV 1536 = 2 exact rounds of 768 resident.
// LDS: two 64B rows per 128B line, 16B-chunk XOR swizzle (inverse-swizzled global
// source + swizzled ds_read) -> fragment reads are bank-conflict-free.
// MODE 0: QKV epilogue -> Q [B,H,S,D] (scaled), K [B,H,S,D], Vt [B,H,D,S]
// MODE 1: f32 epilogue -> Outf[m*N+f] = acc + bias[f]
template <int MODE>
__launch_bounds__(256, 3)
__global__ void gemm_pipe(const bf16_t* __restrict__ A, const bf16_t* __restrict__ Bm,
                          const float* __restrict__ bias,
                          int M, int N,
                          bf16_t* __restrict__ Qg, bf16_t* __restrict__ Kg,
                          bf16_t* __restrict__ Vtg, float* __restrict__ Outf) {
    constexpr int K = 1024, BK = 32, NKT = K / BK;   // 32 K-tiles
    constexpr int BM = 128, BN = 128;
    __shared__ __align__(16) bf16_t As[3][BM * BK];  // 3 x 8 KiB
    __shared__ __align__(16) bf16_t Bs[3][BN * BK];  // 3 x 8 KiB

    // bijective XCD swizzle (grid % 8 == 0 for all our launches)
    const int nwg = gridDim.x;
    const int cpx = nwg >> 3;
    const int bid = (blockIdx.x & 7) * cpx + (blockIdx.x >> 3);

    const int nTN = N / BN;
    const int mt = bid / nTN, nt = bid % nTN;
    const int m0 = mt * BM, n0 = nt * BN;

    const int t = threadIdx.x;
    const int lane = t & 63;
    const int wid = t >> 6;                 // 0..3
    const int wr = wid >> 1, wc = wid & 1;  // 2M x 2N
    const int lr = lane & 15, lg = lane >> 4;

    // ---- staging sources (inverse-swizzled global addresses, linear LDS dest) ----
    // 16B chunk c: line = c>>3, ch = c&7; global chunk chg = ch ^ (line&7);
    // global row = 2*line + (chg>>2), k-offset = (chg&3)*8.
    auto mkSrc = [&](const bf16_t* base, int c, int row0) {
        const int line = c >> 3, chg = (c & 7) ^ (line & 7);
        return base + (int64_t)(row0 + 2 * line + (chg >> 2)) * K + (chg & 3) * 8;
    };
    const bf16_t* aSrc0 = mkSrc(A, t, m0);
    const bf16_t* aSrc1 = mkSrc(A, t + 256, m0);
    const bf16_t* bSrc0 = mkSrc(Bm, t, n0);
    const bf16_t* bSrc1 = mkSrc(Bm, t + 256, n0);

    auto stageT = [&](int kt, int buf) {
        gload_lds16(aSrc0 + kt * BK, &As[buf][t * 8]);
        gload_lds16(aSrc1 + kt * BK, &As[buf][(t + 256) * 8]);
        gload_lds16(bSrc0 + kt * BK, &Bs[buf][t * 8]);
        gload_lds16(bSrc1 + kt * BK, &Bs[buf][(t + 256) * 8]);
    };

    // swizzled fragment element offset for (row, k-chunk kc)
    auto fragOff = [](int row, int kc) -> int {
        const int line = row >> 1;
        const int ch = ((row & 1) << 2) | kc;
        return line * 64 + ((ch ^ (line & 7)) << 3);
    };

    f32x4 acc[4][4] = {};

    stageT(0, 0);
    stageT(1, 1);

    int bufc = 0, bufs = 2;
    for (int kt = 0; kt < NKT; ++kt) {
        if (kt < NKT - 1) wait_vm4(); else wait_vm0();
        __builtin_amdgcn_s_barrier();
        __builtin_amdgcn_sched_barrier(0);

        if (kt + 2 < NKT) stageT(kt + 2, bufs);

        bf16x8 bfr[4], afr[4];
#pragma unroll
        for (int j = 0; j < 4; ++j)
            bfr[j] = *(const bf16x8*)&Bs[bufc][fragOff(wc * 64 + j * 16 + lr, lg)];
#pragma unroll
        for (int i = 0; i < 4; ++i)
            afr[i] = *(const bf16x8*)&As[bufc][fragOff(wr * 64 + i * 16 + lr, lg)];

        __builtin_amdgcn_s_setprio(1);
#pragma unroll
        for (int i = 0; i < 4; ++i)
#pragma unroll
            for (int j = 0; j < 4; ++j)
                acc[i][j] = __builtin_amdgcn_mfma_f32_16x16x32_bf16(afr[i], bfr[j], acc[i][j], 0, 0, 0);
        __builtin_amdgcn_s_setprio(0);

        bufc = (bufc == 2) ? 0 : bufc + 1;
        bufs = (bufs == 2) ? 0 : bufs + 1;
    }

    // ---------------- epilogue ----------------
    if (MODE == 0) {
        const int which = n0 >> 10;   // 0=Q 1=K 2=V (tiles never straddle)
#pragma unroll
        for (int j = 0; j < 4; ++j) {
            const int f = n0 + wc * 64 + j * 16 + lr;
            const float bv = bias[f];
            const int fe = f - which * E_;
            const int h = fe >> 6, d = fe & 63;
#pragma unroll
            for (int i = 0; i < 4; ++i) {
#pragma unroll
                for (int r = 0; r < 4; ++r) {
                    const int m = m0 + wr * 64 + i * 16 + lg * 4 + r;
                    const int b = m >> 11, si = m & (S_ - 1);
                    const float v = acc[i][j][r] + bv;
                    if (which == 0)
                        Qg[(((int64_t)(b * H_ + h)) * S_ + si) * D_ + d] = (bf16_t)(v * QSCALE);
                    else if (which == 1)
                        Kg[(((int64_t)(b * H_ + h)) * S_ + si) * D_ + d] = (bf16_t)v;
                    else
                        Vtg[(((int64_t)(b * H_ + h)) * D_ + d) * S_ + si] = (bf16_t)v;
                }
            }
        }
    } else {
#pragma unroll
        for (int j = 0; j < 4; ++j) {
            const int f = n0 + wc * 64 + j * 16 + lr;
            const float bv = bias[f];
#pragma unroll
            for (int i = 0; i < 4; ++i) {
#pragma unroll
                for (int r = 0; r < 4; ++r) {
                    const int m = m0 + wr * 64 + i * 16 + lg * 4 + r;
                    Outf[(int64_t)m * N + f] = acc[i][j][r] + bv;
                }
            }
        }
    }
}

// ---------------- flash-style causal attention, work-balanced pairs ----------------
// No-max softmax (scores bounded far below f32-exp overflow); Q pre-scaled by
// log2(e)/sqrt(D) so p = 2^s via one v_exp_f32. Row-sum via ones-MFMA.
__launch_bounds__(256, 4)
__global__ void attn_causal(const bf16_t* __restrict__ Qg, const bf16_t* __restrict__ Kg,
                            const bf16_t* __restrict__ Vtg, bf16_t* __restrict__ Og) {
    __shared__ __align__(16) bf16_t Ks[2][64 * 64];   // 16 KiB
    __shared__ __align__(16) bf16_t Vs[2][64 * 64];   // 16 KiB
    __shared__ __align__(16) bf16_t P_lds[4][16 * 64]; // 8 KiB, swizzled

    const int bid = blockIdx.x;
    const int xcd = bid & 7, j = bid >> 3;
    const int bh = (j >> 4) * 8 + xcd;
    const int i = j & 15;
    const int qtA = i, qtB = 31 - i;

    const int t = threadIdx.x, lane = t & 63, w = t >> 6;
    const int lr = lane & 15, lg = lane >> 4;
    const int q0A = qtA * 64 + w * 16;
    const int q0B = qtB * 64 + w * 16;

    const bf16_t* Qb = Qg + (int64_t)bh * S_ * D_;
    const bf16_t* Kb = Kg + (int64_t)bh * S_ * D_;
    const bf16_t* Vb = Vtg + (int64_t)bh * D_ * S_;

    const int srow = t >> 3;
    const int scol_sw = (t & 7) ^ (srow & 7);

    auto stageK = [&](int buf, int kv0) {
        const bf16_t* base = Kb + (kv0 + srow) * D_ + scol_sw * 8;
        gload_lds16(base, &Ks[buf][t * 8]);
        gload_lds16(base + 32 * D_, &Ks[buf][t * 8 + 2048]);
    };
    auto stageV = [&](int buf, int kv0) {
        const bf16_t* base = Vb + srow * S_ + kv0 + scol_sw * 8;
        gload_lds16(base, &Vs[buf][t * 8]);
        gload_lds16(base + 32 * S_, &Vs[buf][t * 8 + 2048]);
    };

    auto psw = [](int row, int col) {
        return row * 64 + ((((col >> 3) ^ (row & 7)) << 3) | (col & 7));
    };

    bf16x8 qfA[2], qfB[2];
#pragma unroll
    for (int kk = 0; kk < 2; ++kk) {
        qfA[kk] = *(const bf16x8*)&Qb[(q0A + lr) * D_ + kk * 32 + lg * 8];
        qfB[kk] = *(const bf16x8*)&Qb[(q0B + lr) * D_ + kk * 32 + lg * 8];
    }

    bf16x8 ones;
#pragma unroll
    for (int e = 0; e < 8; ++e) ones[e] = (bf16_t)1.0f;

    f32x4 oA[4] = {}, oB[4] = {};
    f32x4 lA = {}, lB = {};

    int cur = 0;
    stageK(0, 0);
    stageV(0, 0);
    __syncthreads();

    for (int tkv = 0; tkv <= qtB; ++tkv) {
        const int kv0 = tkv * 64;
        if (tkv < qtB) { stageK(cur ^ 1, kv0 + 64); stageV(cur ^ 1, kv0 + 64); }

        auto process = [&](int q0, const bf16x8* qf, f32x4* o, f32x4& accl, bf16_t* Pw) {
            f32x4 sc[4] = {};
            __builtin_amdgcn_s_setprio(1);
#pragma unroll
            for (int nj = 0; nj < 4; ++nj) {
                if (kv0 + nj * 16 <= q0 + 15) {   // skip fully-masked sub-tiles (wave-uniform)
                    const int krow = nj * 16 + lr;
#pragma unroll
                    for (int kk = 0; kk < 2; ++kk) {
                        bf16x8 kfr = *(const bf16x8*)&Ks[cur][krow * 64 + (((kk * 4 + lg) ^ (krow & 7)) * 8)];
                        sc[nj] = __builtin_amdgcn_mfma_f32_16x16x32_bf16(qf[kk], kfr, sc[nj], 0, 0, 0);
                    }
                }
            }
            __builtin_amdgcn_s_setprio(0);

            if (kv0 + 64 > q0) {  // causal mask (boundary tile only)
#pragma unroll
                for (int nj = 0; nj < 4; ++nj) {
                    const int col = kv0 + nj * 16 + lr;
#pragma unroll
                    for (int r = 0; r < 4; ++r) {
                        const int rowg = q0 + lg * 4 + r;
                        if (col > rowg) sc[nj][r] = -1e30f;
                    }
                }
            }

            // p = 2^s; masked -> 0
#pragma unroll
            for (int nj = 0; nj < 4; ++nj)
#pragma unroll
                for (int r = 0; r < 4; ++r)
                    Pw[psw(lg * 4 + r, nj * 16 + lr)] = (bf16_t)__builtin_amdgcn_exp2f(sc[nj][r]);
            asm volatile("s_waitcnt lgkmcnt(0)" ::: "memory");
            __builtin_amdgcn_sched_barrier(0);

            __builtin_amdgcn_s_setprio(1);
#pragma unroll
            for (int kk = 0; kk < 2; ++kk) {
                bf16x8 pa = *(const bf16x8*)&Pw[psw(lr, kk * 32 + lg * 8)];
                accl = __builtin_amdgcn_mfma_f32_16x16x32_bf16(pa, ones, accl, 0, 0, 0);
#pragma unroll
                for (int nd = 0; nd < 4; ++nd) {
                    const int vrow = nd * 16 + lr;
                    bf16x8 vf = *(const bf16x8*)&Vs[cur][vrow * 64 + (((kk * 4 + lg) ^ (vrow & 7)) * 8)];
                    o[nd] = __builtin_amdgcn_mfma_f32_16x16x32_bf16(pa, vf, o[nd], 0, 0, 0);
                }
            }
            __builtin_amdgcn_s_setprio(0);
        };

        process(q0B, qfB, oB, lB, &P_lds[w][0]);
        if (tkv <= qtA) process(q0A, qfA, oA, lA, &P_lds[w][0]);

        __syncthreads();
        cur ^= 1;
    }

    const int b = bh >> 4, h = bh & 15;
#pragma unroll
    for (int r = 0; r < 4; ++r) {
        const float rlA = 1.0f / lA[r];
        const float rlB = 1.0f / lB[r];
        const int rA = q0A + lg * 4 + r;
        const int rB = q0B + lg * 4 + r;
#pragma unroll
        for (int nd = 0; nd < 4; ++nd) {
            Og[((int64_t)(b * S_ + rA)) * E_ + h * D_ + nd * 16 + lr] = (bf16_t)(oA[nd][r] * rlA);
            Og[((int64_t)(b * S_ + rB)) * E_ + h * D_ + nd * 16 + lr] = (bf16_t)(oB[nd][r] * rlB);
        }
    }
}

// ---------------- launch ----------------
extern "C" void kernel_launch(void* const* d_in, const int* in_sizes, int n_in,
                              void* d_out, int out_size, void* d_ws, size_t ws_size,
                              hipStream_t stream) {
    const float* x    = (const float*)d_in[0];
    const float* Wa_w = (const float*)d_in[1];
    const float* Wa_b = (const float*)d_in[2];
    const float* Wo_w = (const float*)d_in[3];
    const float* Wo_b = (const float*)d_in[4];
    float* out = (float*)d_out;

    const size_t M = (size_t)B_ * S_;       // 8192
    char* ws = (char*)d_ws;
    bf16_t* xb  = (bf16_t*)ws; ws += M * E_ * 2;
    bf16_t* wab = (bf16_t*)ws; ws += (size_t)3 * E_ * E_ * 2;
    bf16_t* wob = (bf16_t*)ws; ws += (size_t)E_ * E_ * 2;
    bf16_t* Qg  = (bf16_t*)ws; ws += M * E_ * 2;
    bf16_t* Kg  = (bf16_t*)ws; ws += M * E_ * 2;
    bf16_t* Vtg = (bf16_t*)ws; ws += M * E_ * 2;
    bf16_t* Og  = (bf16_t*)ws; ws += M * E_ * 2;

    cvt_f32_to_bf16<<<2048, 256, 0, stream>>>(x, xb, (int)(M * E_ / 4));
    cvt_f32_to_bf16<<<768, 256, 0, stream>>>(Wa_w, wab, 3 * E_ * E_ / 4);
    cvt_f32_to_bf16<<<256, 256, 0, stream>>>(Wo_w, wob, E_ * E_ / 4);

    // QKV projection: M=8192, N=3072 -> 64 x 24 = 1536 blocks (2 exact rounds at 3/CU)
    gemm_pipe<0><<<1536, 256, 0, stream>>>(
        xb, wab, Wa_b, 8192, 3072, Qg, Kg, Vtg, nullptr);

    // causal attention (work-balanced pairs, 4 blocks/CU, zero tail, no-max softmax)
    attn_causal<<<B_ * H_ * 16, 256, 0, stream>>>(Qg, Kg, Vtg, Og);

    // output projection: M=8192, N=1024 -> 64 x 8 = 512 blocks (all resident)
    gemm_pipe<1><<<512, 256, 0, stream>>>(
        Og, wob, Wo_b, 8192, 1024, nullptr, nullptr, nullptr, out);
}